// Round 5
// baseline (625.909 us; speedup 1.0000x reference)
//
#include <hip/hip_runtime.h>

#define BB 4
#define HH 352
#define WW 1216
#define HW (HH * WW)
#define NPIX (BB * HW)   // 1,712,128
#define TX 4             // pixels per thread in conv kernel

// Padded propagation buffer: apron of zeros so bilinear gathers need no
// bounds checks. |rel| <= 4 (encode clamp) => corners in [y-4,y+5]x[x-4,x+5].
#define PAD_T 5
#define PAD_L 8
#define HP (HH + 2 * PAD_T)      // 362
#define WP (WW + 2 * PAD_L)      // 1232
#define HWP (HP * WP)            // 445,984

// Prop LDS tile: block covers 64x4 px; samples live in 13 rows x 73 cols;
// stride 76 (banks shift by 12/row; scattered reads ~2 lanes/bank = free).
#define TROWS 13
#define TCOLS 76
#define TSIZE (TROWS * TCOLS)    // 988

// SoA tap tables:
//   affp  [9][NPIX] u16 : modulation, q=round((a+1)*20000), res 5e-5.
//   coordp[8][NPIX] u32 : packed coords, q=round((rel+4)*8192), y lo, x hi.
// Neighbor n -> prop tap k = (n<4 ? n : n+1).
//
// NOTES carried forward:
//  R3: every loop indexing a register array MUST be fully unrolled (runtime
//      index -> scratch demotion, 5.4 GB spill, 8x regression).
//  R5: WRITE_SIZE includes ~160 MB of harness 0xAA-poison writeback.
//  R7: prop is NOT HBM-bound at 27 us/step (-26% bytes -> 0 time change).
//  R8: LDS tile staging, gathers via ds_read2_b32 (prop now ~23.5 us/step).
//  R9: merged conv (acc[24][2], 320 thr) -> AGPR demotion, VALU 145us.
//  R10: TX=1 + launch_bounds(320,4) -> VGPR_Count 32, VALU 203us. Allocator
//       chases occupancy hints into AGPR hell.
//  R11: role-fused = 147.6us. Cost model: pass = L(19us loads) + F(33us per
//       8-out slab); merging amortizes L but 320-thr blocks are PINNED at 52
//       arch VGPR -> any acc > ~32 floats spills to AGPR.
//  R12: 3x8-out roles = 165us = 3L+3F. Splitting multiplies L. Confirmed.
//  R13 (this round): 64-thread blocks + __launch_bounds__(64,1) = explicit
//       max-register request (1 wave/EU -> 512-reg budget). Full 24-out merged
//       conv in ~150 ARCH VGPRs, no AGPR churn. Tell: VGPR_Count >= 128.

// ---------------------------------------------------------------------------
// Kernel A: merged 3x3 conv, all 24 outputs, one wave per block.
// Block = 64 threads, TX=4 -> 256 px span; 5 blocks per row (last masked).
// Grid = 1408 rows x 5 = 7040, XCD-swizzled (176 rows per XCD).
// Channel mapping (verified R2): neighbor n: dy = ch[2n], dx = ch[2n+1];
// aff pre-activation for neighbor n = ch[16+n]. Numerics = R9 (passed).
// ---------------------------------------------------------------------------
__global__ __launch_bounds__(64, 1) void conv_merged64_kernel(
    const float* __restrict__ guid, const float* __restrict__ w,
    const float* __restrict__ bias, const float* __restrict__ scale_p,
    unsigned* __restrict__ coordp, unsigned short* __restrict__ affp)
{
    int tid = threadIdx.x;
    int bid = blockIdx.x;                  // 0..7039
    int xcd = bid & 7;
    int u = bid >> 3;                      // 0..879
    int row = xcd * 176 + u / 5;           // 0..1407
    int blk = u % 5;
    int y = row % HH;
    int b = row / HH;
    int x0 = blk * 256 + tid * TX;
    if (x0 >= WW) return;                  // tail block: threads 48..63 idle
    const float* gb = guid + (size_t)b * 8 * HW;

    float acc[24][TX];
#pragma unroll
    for (int o = 0; o < 24; ++o) {
        float bv = bias[o];
#pragma unroll
        for (int tx = 0; tx < TX; ++tx) acc[o][tx] = bv;
    }

    // Per-channel 3x6 window loader (global cols x0-1 .. x0+4).
    auto load_ch = [&](float (&dst)[3][6], int cc) {
#pragma unroll
        for (int r = 0; r < 3; ++r) {
            int yy = y + r - 1;
            bool rv = (yy >= 0) && (yy < HH);   // uniform per block
            const float* gr = gb + (size_t)cc * HW + (size_t)yy * WW;
            if (rv) {
                const float4 m = *(const float4*)(gr + x0);
                dst[r][1] = m.x; dst[r][2] = m.y; dst[r][3] = m.z; dst[r][4] = m.w;
                dst[r][0] = (x0 > 0) ? gr[x0 - 1] : 0.f;
                dst[r][5] = (x0 + TX < WW) ? gr[x0 + TX] : 0.f;
            } else {
#pragma unroll
                for (int i = 0; i < 6; ++i) dst[r][i] = 0.f;
            }
        }
    };

    float g[3][6];
    load_ch(g, 0);

#pragma unroll 1
    for (int c = 0; c < 8; ++c) {
        // Prefetch next channel; 864 FMAs below cover the latency.
        float gn[3][6];
        if (c < 7) load_ch(gn, c + 1);

#pragma unroll
        for (int r = 0; r < 3; ++r) {
#pragma unroll
            for (int i = 0; i < 3; ++i) {
                int tap = r * 3 + i;
#pragma unroll
                for (int o = 0; o < 24; ++o) {
                    float wv = w[o * 72 + c * 9 + tap];  // uniform -> s_load
#pragma unroll
                    for (int tx = 0; tx < TX; ++tx)
                        acc[o][tx] = fmaf(wv, g[r][i + tx], acc[o][tx]);
                }
            }
        }
        if (c < 7) {
#pragma unroll
            for (int r = 0; r < 3; ++r)
#pragma unroll
                for (int i = 0; i < 6; ++i) g[r][i] = gn[r][i];
        }
    }

    int idx0 = row * WW + x0;

    // --- offsets epilogue (R0 verbatim) -----------------------------------
#pragma unroll
    for (int n = 0; n < 8; ++n) {
        int k = (n < 4) ? n : n + 1;
        float ky = (float)(k / 3 - 1), kx = (float)(k % 3 - 1);
        unsigned cw[TX];
#pragma unroll
        for (int tx = 0; tx < TX; ++tx) {
            float yr = ky + acc[2 * n][tx];
            float xr = kx + acc[2 * n + 1][tx];
            int yq = (int)lrintf((yr + 4.f) * 8192.f);
            int xq = (int)lrintf((xr + 4.f) * 8192.f);
            yq = min(max(yq, 0), 65535);
            xq = min(max(xq, 0), 65535);
            cw[tx] = (unsigned)yq | ((unsigned)xq << 16);
        }
        uint4 v = make_uint4(cw[0], cw[1], cw[2], cw[3]);
        *(uint4*)(coordp + (size_t)n * NPIX + idx0) = v;
    }

    // --- TGASS affinity epilogue (R0 verbatim, acc rows 16..23) -----------
    float sc = scale_p[0] + 1e-8f;
    unsigned short av[9][TX];
#pragma unroll
    for (int tx = 0; tx < TX; ++tx) {
        float a[8];
        float asum = 1e-4f;
#pragma unroll
        for (int n = 0; n < 8; ++n) {
            a[n] = tanhf(acc[16 + n][tx]) / sc;
            asum += fabsf(a[n]);
        }
        asum = fmaxf(asum, 1.0f);
        float ssum = 0.f;
#pragma unroll
        for (int n = 0; n < 8; ++n) { a[n] = a[n] / asum; ssum += a[n]; }
        float aref = 1.0f - ssum;
#pragma unroll
        for (int k = 0; k < 9; ++k) {
            float aval = (k == 4) ? aref : a[(k < 4) ? k : k - 1];
            int q = (int)lrintf((aval + 1.f) * 20000.f);
            q = min(max(q, 0), 65535);
            av[k][tx] = (unsigned short)q;
        }
    }
#pragma unroll
    for (int k = 0; k < 9; ++k) {
        ushort4 v = make_ushort4(av[k][0], av[k][1], av[k][2], av[k][3]);
        *(ushort4*)(affp + (size_t)k * NPIX + idx0) = v;
    }
}

// ---------------------------------------------------------------------------
// Kernel B: one propagation step. Block = 64x4 px; feat tile (13x76) staged
// in LDS, all bilinear corner reads served by ds_read2_b32 pairs instead of
// divergent global gathers (R7: gather pipe was the bottleneck).
// XCD swizzle: xcd = bid&7 owns 11 contiguous 4-row y-bands -> featc slice
// L2-resident (R6).
// Tile coords: sample row = ly + qy/8192 (the -4 of rel cancels the tile
// origin at y-4); valid range rows [0,12], cols [0,72] within 13x76.
// ---------------------------------------------------------------------------
template <bool MULCONF>
__global__ __launch_bounds__(256) void prop_step_kernel(
    const float* __restrict__ fsrc, const unsigned short* __restrict__ affp,
    const unsigned* __restrict__ coordp, const float* __restrict__ conf,
    float* __restrict__ dst)
{
    __shared__ float tile[TSIZE];

    int bid = blockIdx.x;                 // 6688 blocks = 8 * 836
    int xcd = bid & 7;
    int s = bid >> 3;                     // 0..835
    int yband = xcd * 11 + s % 11;        // 0..87
    int rest = s / 11;                    // 0..75
    int xb = rest % 19;
    int b = rest / 19;
    int t = threadIdx.x;
    int lx = t & 63, ly = t >> 6;
    int x = xb * 64 + lx;
    int y = yband * 4 + ly;
    int idx = (b * HH + y) * WW + x;

    // Hoist independent table loads so they fly across the staging barrier.
    unsigned cw[8];
#pragma unroll
    for (int n = 0; n < 8; ++n) cw[n] = coordp[(size_t)n * NPIX + idx];
    float ak[9];
#pragma unroll
    for (int k = 0; k < 9; ++k)
        ak[k] = fmaf((float)affp[(size_t)k * NPIX + idx], 5e-5f, -1.f);
    float cv = MULCONF ? conf[idx] : 0.f;

    // Stage tile: unpadded rows [y0-4, y0+8], cols [x0-4, x0+71]; all inside
    // the padded buffer (row y0-4 -> padded y0+1 >= 1; col x0-4 -> x0+4).
    {
        const float* gsrc = fsrc + (size_t)b * HWP
                          + (size_t)(yband * 4 + 1) * WP + (xb * 64 + 4);
        for (int i = t; i < TSIZE; i += 256)
            tile[i] = gsrc[(i / TCOLS) * WP + (i % TCOLS)];
    }
    __syncthreads();

    float fy = (float)ly;
    float fx = (float)lx;
    float res = ak[4] * tile[(ly + 4) * TCOLS + (lx + 4)];  // exact center tap
#pragma unroll
    for (int n = 0; n < 8; ++n) {
        float ys = fmaf((float)(cw[n] & 0xffffu), 1.f / 8192.f, fy);
        float xs = fmaf((float)(cw[n] >> 16),     1.f / 8192.f, fx);
        float y0f = floorf(ys), x0f = floorf(xs);
        float wy1 = ys - y0f, wx1 = xs - x0f;
        float wy0 = 1.f - wy1, wx0 = 1.f - wx1;
        int o = (int)y0f * TCOLS + (int)x0f;
        float v00 = tile[o],         v01 = tile[o + 1];          // ds_read2
        float v10 = tile[o + TCOLS], v11 = tile[o + TCOLS + 1];  // ds_read2
        float sv = wy0 * (wx0 * v00 + wx1 * v01) + wy1 * (wx0 * v10 + wx1 * v11);
        int k = (n < 4) ? n : n + 1;
        res = fmaf(ak[k], sv, res);
    }
    if (MULCONF) {
        res *= cv;
        dst[(size_t)b * HWP + (y + PAD_T) * WP + (x + PAD_L)] = res;
    } else {
        dst[idx] = res;
    }
}

// Zero both padded buffers (apron must be 0; ws is poisoned 0xAA each launch).
__global__ __launch_bounds__(256) void zero_kernel(float4* __restrict__ p, int n4)
{
    int i = blockIdx.x * blockDim.x + threadIdx.x;
    if (i < n4) p[i] = make_float4(0.f, 0.f, 0.f, 0.f);
}

// fc0[padded interior] = feat_init * conf
__global__ __launch_bounds__(256) void mulpad_kernel(
    const float* __restrict__ a, const float* __restrict__ c, float* __restrict__ o)
{
    int t = threadIdx.x;
    int x = blockIdx.x * 64 + (t & 63);
    int y = blockIdx.y * 4 + (t >> 6);
    int b = blockIdx.z;
    int idx = (b * HH + y) * WW + x;
    o[(size_t)b * HWP + (y + PAD_T) * WP + (x + PAD_L)] = a[idx] * c[idx];
}

extern "C" void kernel_launch(void* const* d_in, const int* in_sizes, int n_in,
                              void* d_out, int out_size, void* d_ws, size_t ws_size,
                              hipStream_t stream)
{
    const float* feat_init  = (const float*)d_in[0];
    const float* guidance   = (const float*)d_in[1];
    const float* confidence = (const float*)d_in[2];
    const float* w_oa       = (const float*)d_in[3];
    const float* b_oa       = (const float*)d_in[4];
    const float* aff_scale  = (const float*)d_in[5];
    float* out = (float*)d_out;

    // Workspace: affp u16[9N] | coordp u32[8N] | fc0p f32[BB*HWP] | fc1p
    const size_t N = (size_t)NPIX;
    unsigned short* affp = (unsigned short*)d_ws;
    unsigned* coordp = (unsigned*)(affp + 9 * N);
    float* fc0 = (float*)(coordp + 8 * N);
    float* fc1 = fc0 + (size_t)BB * HWP;

    const dim3 mgrid(WW / 64, HH / 4, BB);
    const int n4 = 2 * BB * HWP / 4;
    zero_kernel<<<(n4 + 255) / 256, 256, 0, stream>>>((float4*)fc0, n4);
    mulpad_kernel<<<mgrid, 256, 0, stream>>>(feat_init, confidence, fc0);
    conv_merged64_kernel<<<5 * BB * HH, 64, 0, stream>>>(
        guidance, w_oa, b_oa, aff_scale, coordp, affp);

    const int pblocks = (WW / 64) * (HH / 4) * BB;   // 6688
    float* bufs[2] = {fc0, fc1};
    const int T = 18;
    for (int i = 0; i < T; ++i) {
        const float* src = bufs[i & 1];
        if (i < T - 1) {
            float* dst = bufs[(i + 1) & 1];
            prop_step_kernel<true><<<pblocks, 256, 0, stream>>>(
                src, affp, coordp, confidence, dst);
        } else {
            prop_step_kernel<false><<<pblocks, 256, 0, stream>>>(
                src, affp, coordp, confidence, out);
        }
    }
}

// Round 6
// 558.334 us; speedup vs baseline: 1.1210x; 1.1210x over previous
//
#include <hip/hip_runtime.h>

#define BB 4
#define HH 352
#define WW 1216
#define HW (HH * WW)
#define NPIX (BB * HW)   // 1,712,128
#define TX 4             // pixels per thread in conv kernels (1216 = 4*304)

// Padded propagation buffer: apron of zeros so bilinear gathers need no
// bounds checks. |rel| <= 4 (encode clamp) => corners in [y-4,y+5]x[x-4,x+5].
#define PAD_T 5
#define PAD_L 8
#define HP (HH + 2 * PAD_T)      // 362
#define WP (WW + 2 * PAD_L)      // 1232
#define HWP (HP * WP)            // 445,984

// Prop LDS tile: block covers 64x4 px; samples live in 13 rows x 73 cols;
// stride 76 (banks shift by 12/row; scattered reads ~2 lanes/bank = free).
#define TROWS 13
#define TCOLS 76
#define TSIZE (TROWS * TCOLS)    // 988

// AoS tap table (R14): one 48B record per px, 16B-aligned:
//   u32 slot 0..7 : packed coords, q=round((rel+4)*8192), y lo16, x hi16,
//                   neighbor order n=0..7 (tap k = n<4 ? n : n+1).
//   u32 slot 8..11: 8 affinities u16 (taps 0,1,2,3,5,6,7,8), q=(a+1)*20000.
// Center-tap affinity is NOT stored: ak4 = 1 - sum(others) exactly (TGASS
// defines aff_ref = 1 - sum), recomputation error <= 8*2.5e-5 = 2e-4.
// Prop reads the whole record with 3 dwordx4 loads off one base (was 17
// plane loads + 64-bit addr math each; R7: prop is issue/latency-bound,
// not bytes-bound, so layout beats compression).
//
// NOTES carried forward:
//  R3: every loop indexing a register array MUST be fully unrolled (runtime
//      index -> scratch demotion, 5.4 GB spill, 8x regression).
//  R5: WRITE_SIZE includes ~160 MB of harness 0xAA-poison writeback.
//  R7: prop is NOT HBM-bound at 27 us/step (-26% bytes -> 0 time change).
//  R8: LDS tile staging, gathers via ds_read2_b32 (prop now ~23.5 us/step).
//  R9/R10/R13: merged 24-out conv DEAD END: allocator caps conv blocks at
//      52-100 arch VGPR regardless of launch_bounds; acc > ~32 floats ->
//      AGPR demotion -> 3-5 VALU ops per FMA (145-203 us VALU vs 38 floor).
//  R11: 2-role fused conv = 147.6 us, best known. KEEP.
//  R12: 3x8-out roles = 165 us (splitting multiplies the fixed load cost).
//  R14 (this round): conv reverted to R11 exactly; table layout -> 48B AoS.

// ---------------------------------------------------------------------------
// Kernel A (role-fused): grid 2816 = 2 roles x 1408 rows.
//   xcd = bid&7, j = bid>>3 (0..351), role = j&1, row = xcd*176 + (j>>1).
// role 0: offsets pass (ch 0..15 -> coord slots 0..7), R3 body verbatim.
// role 1: affinity pass (ch 16..23 + TGASS -> aff slots 8..11).
// Channel mapping (verified R2): neighbor n: dy = ch[2n], dx = ch[2n+1].
// ---------------------------------------------------------------------------
__global__ __launch_bounds__(320) void conv_fused_kernel(
    const float* __restrict__ guid, const float* __restrict__ w,
    const float* __restrict__ bias, const float* __restrict__ scale_p,
    unsigned* __restrict__ tab)
{
    int tid = threadIdx.x;
    if (tid >= WW / TX) return;            // 304 active
    int bid = blockIdx.x;                  // 0..2815
    int xcd = bid & 7;
    int j = bid >> 3;                      // 0..351
    int role = j & 1;                      // block-uniform
    int row = xcd * 176 + (j >> 1);        // 0..1407, 176 rows per XCD
    int y = row % HH;
    int b = row / HH;
    int x0 = tid * TX;
    const float* gb = guid + (size_t)b * 8 * HW;

    if (role == 0) {
        // ---------------- offsets body (R3 verbatim) ----------------------
        float acc[16][TX];
#pragma unroll
        for (int o = 0; o < 16; ++o) {
            float bv = bias[o];
#pragma unroll
            for (int tx = 0; tx < TX; ++tx) acc[o][tx] = bv;
        }

#pragma unroll 1
        for (int c = 0; c < 8; ++c) {
            float g[3][6];
#pragma unroll
            for (int r = 0; r < 3; ++r) {
                int yy = y + r - 1;
                bool rv = (yy >= 0) && (yy < HH);   // uniform per block
                const float* gr = gb + (size_t)c * HW + (size_t)yy * WW;
                if (rv) {
                    const float4 m = *(const float4*)(gr + x0);
                    g[r][1] = m.x; g[r][2] = m.y; g[r][3] = m.z; g[r][4] = m.w;
                    g[r][0] = (x0 > 0) ? gr[x0 - 1] : 0.f;
                    g[r][5] = (x0 + TX < WW) ? gr[x0 + TX] : 0.f;
                } else {
#pragma unroll
                    for (int i = 0; i < 6; ++i) g[r][i] = 0.f;
                }
            }
#pragma unroll
            for (int r = 0; r < 3; ++r) {
#pragma unroll
                for (int i = 0; i < 3; ++i) {
                    int tap = r * 3 + i;
#pragma unroll
                    for (int o = 0; o < 16; ++o) {
                        float wv = w[o * 72 + c * 9 + tap];  // uniform -> s_load
#pragma unroll
                        for (int tx = 0; tx < TX; ++tx)
                            acc[o][tx] = fmaf(wv, g[r][i + tx], acc[o][tx]);
                    }
                }
            }
        }

        int idx0 = row * WW + x0;
#pragma unroll
        for (int tx = 0; tx < TX; ++tx) {
            unsigned cw8[8];
#pragma unroll
            for (int n = 0; n < 8; ++n) {
                int k = (n < 4) ? n : n + 1;
                float ky = (float)(k / 3 - 1), kx = (float)(k % 3 - 1);
                float yr = ky + acc[2 * n][tx];
                float xr = kx + acc[2 * n + 1][tx];
                int yq = (int)lrintf((yr + 4.f) * 8192.f);
                int xq = (int)lrintf((xr + 4.f) * 8192.f);
                yq = min(max(yq, 0), 65535);
                xq = min(max(xq, 0), 65535);
                cw8[n] = (unsigned)yq | ((unsigned)xq << 16);
            }
            unsigned* tp = tab + (size_t)(idx0 + tx) * 12;
            *(uint4*)(tp)     = make_uint4(cw8[0], cw8[1], cw8[2], cw8[3]);
            *(uint4*)(tp + 4) = make_uint4(cw8[4], cw8[5], cw8[6], cw8[7]);
        }
    } else {
        // ---------------- affinity body (R3 verbatim) ---------------------
        float acc[8][TX];
#pragma unroll
        for (int o = 0; o < 8; ++o) {
            float bv = bias[16 + o];
#pragma unroll
            for (int tx = 0; tx < TX; ++tx) acc[o][tx] = bv;
        }

#pragma unroll 1
        for (int c = 0; c < 8; ++c) {
            float g[3][6];
#pragma unroll
            for (int r = 0; r < 3; ++r) {
                int yy = y + r - 1;
                bool rv = (yy >= 0) && (yy < HH);
                const float* gr = gb + (size_t)c * HW + (size_t)yy * WW;
                if (rv) {
                    const float4 m = *(const float4*)(gr + x0);
                    g[r][1] = m.x; g[r][2] = m.y; g[r][3] = m.z; g[r][4] = m.w;
                    g[r][0] = (x0 > 0) ? gr[x0 - 1] : 0.f;
                    g[r][5] = (x0 + TX < WW) ? gr[x0 + TX] : 0.f;
                } else {
#pragma unroll
                    for (int i = 0; i < 6; ++i) g[r][i] = 0.f;
                }
            }
#pragma unroll
            for (int r = 0; r < 3; ++r) {
#pragma unroll
                for (int i = 0; i < 3; ++i) {
                    int tap = r * 3 + i;
#pragma unroll
                    for (int o = 0; o < 8; ++o) {
                        float wv = w[(16 + o) * 72 + c * 9 + tap];
#pragma unroll
                        for (int tx = 0; tx < TX; ++tx)
                            acc[o][tx] = fmaf(wv, g[r][i + tx], acc[o][tx]);
                    }
                }
            }
        }

        float sc = scale_p[0] + 1e-8f;
        int idx0 = row * WW + x0;
#pragma unroll
        for (int tx = 0; tx < TX; ++tx) {
            float a[8];
            float asum = 1e-4f;
#pragma unroll
            for (int n = 0; n < 8; ++n) {
                a[n] = tanhf(acc[n][tx]) / sc;
                asum += fabsf(a[n]);
            }
            asum = fmaxf(asum, 1.0f);
            unsigned q8[8];
#pragma unroll
            for (int n = 0; n < 8; ++n) {
                a[n] = a[n] / asum;
                int q = (int)lrintf((a[n] + 1.f) * 20000.f);
                q = min(max(q, 0), 65535);
                q8[n] = (unsigned)q;
            }
            unsigned* tp = tab + (size_t)(idx0 + tx) * 12 + 8;
            *(uint4*)(tp) = make_uint4(q8[0] | (q8[1] << 16), q8[2] | (q8[3] << 16),
                                       q8[4] | (q8[5] << 16), q8[6] | (q8[7] << 16));
        }
    }
}

// ---------------------------------------------------------------------------
// Kernel B: one propagation step. Block = 64x4 px; feat tile (13x76) staged
// in LDS, all bilinear corner reads served by ds_read2_b32 pairs instead of
// divergent global gathers (R7: gather pipe was the bottleneck).
// Tables: one 48B AoS record per px -> 3 dwordx4 loads (R14).
// XCD swizzle: xcd = bid&7 owns 11 contiguous 4-row y-bands -> featc slice
// L2-resident (R6).
// Tile coords: sample row = ly + qy/8192 (the -4 of rel cancels the tile
// origin at y-4); valid range rows [0,12], cols [0,72] within 13x76.
// ---------------------------------------------------------------------------
template <bool MULCONF>
__global__ __launch_bounds__(256) void prop_step_kernel(
    const float* __restrict__ fsrc, const unsigned* __restrict__ tab,
    const float* __restrict__ conf, float* __restrict__ dst)
{
    __shared__ float tile[TSIZE];

    int bid = blockIdx.x;                 // 6688 blocks = 8 * 836
    int xcd = bid & 7;
    int s = bid >> 3;                     // 0..835
    int yband = xcd * 11 + s % 11;        // 0..87
    int rest = s / 11;                    // 0..75
    int xb = rest % 19;
    int b = rest / 19;
    int t = threadIdx.x;
    int lx = t & 63, ly = t >> 6;
    int x = xb * 64 + lx;
    int y = yband * 4 + ly;
    int idx = (b * HH + y) * WW + x;

    // Whole tap record in 3 aligned dwordx4 loads; they fly across the
    // staging barrier below.
    const unsigned* tp = tab + (size_t)idx * 12;
    uint4 t0 = *(const uint4*)(tp);       // coords n0..3
    uint4 t1 = *(const uint4*)(tp + 4);   // coords n4..7
    uint4 t2 = *(const uint4*)(tp + 8);   // affs u16 x8 (taps 0..3,5..8)
    float cv = MULCONF ? conf[idx] : 0.f;

    // Stage tile: unpadded rows [y0-4, y0+8], cols [x0-4, x0+71]; all inside
    // the padded buffer (row y0-4 -> padded y0+1 >= 1; col x0-4 -> x0+4).
    {
        const float* gsrc = fsrc + (size_t)b * HWP
                          + (size_t)(yband * 4 + 1) * WP + (xb * 64 + 4);
        for (int i = t; i < TSIZE; i += 256)
            tile[i] = gsrc[(i / TCOLS) * WP + (i % TCOLS)];
    }

    unsigned cw[8] = {t0.x, t0.y, t0.z, t0.w, t1.x, t1.y, t1.z, t1.w};
    float ak[9];
    ak[0] = fmaf((float)(t2.x & 0xffffu), 5e-5f, -1.f);
    ak[1] = fmaf((float)(t2.x >> 16),     5e-5f, -1.f);
    ak[2] = fmaf((float)(t2.y & 0xffffu), 5e-5f, -1.f);
    ak[3] = fmaf((float)(t2.y >> 16),     5e-5f, -1.f);
    ak[5] = fmaf((float)(t2.z & 0xffffu), 5e-5f, -1.f);
    ak[6] = fmaf((float)(t2.z >> 16),     5e-5f, -1.f);
    ak[7] = fmaf((float)(t2.w & 0xffffu), 5e-5f, -1.f);
    ak[8] = fmaf((float)(t2.w >> 16),     5e-5f, -1.f);
    ak[4] = 1.f - (((ak[0] + ak[1]) + (ak[2] + ak[3]))
                 + ((ak[5] + ak[6]) + (ak[7] + ak[8])));

    __syncthreads();

    float fy = (float)ly;
    float fx = (float)lx;
    float res = ak[4] * tile[(ly + 4) * TCOLS + (lx + 4)];  // exact center tap
#pragma unroll
    for (int n = 0; n < 8; ++n) {
        float ys = fmaf((float)(cw[n] & 0xffffu), 1.f / 8192.f, fy);
        float xs = fmaf((float)(cw[n] >> 16),     1.f / 8192.f, fx);
        float y0f = floorf(ys), x0f = floorf(xs);
        float wy1 = ys - y0f, wx1 = xs - x0f;
        float wy0 = 1.f - wy1, wx0 = 1.f - wx1;
        int o = (int)y0f * TCOLS + (int)x0f;
        float v00 = tile[o],         v01 = tile[o + 1];          // ds_read2
        float v10 = tile[o + TCOLS], v11 = tile[o + TCOLS + 1];  // ds_read2
        float sv = wy0 * (wx0 * v00 + wx1 * v01) + wy1 * (wx0 * v10 + wx1 * v11);
        int k = (n < 4) ? n : n + 1;
        res = fmaf(ak[k], sv, res);
    }
    if (MULCONF) {
        res *= cv;
        dst[(size_t)b * HWP + (y + PAD_T) * WP + (x + PAD_L)] = res;
    } else {
        dst[idx] = res;
    }
}

// Zero both padded buffers (apron must be 0; ws is poisoned 0xAA each launch).
__global__ __launch_bounds__(256) void zero_kernel(float4* __restrict__ p, int n4)
{
    int i = blockIdx.x * blockDim.x + threadIdx.x;
    if (i < n4) p[i] = make_float4(0.f, 0.f, 0.f, 0.f);
}

// fc0[padded interior] = feat_init * conf
__global__ __launch_bounds__(256) void mulpad_kernel(
    const float* __restrict__ a, const float* __restrict__ c, float* __restrict__ o)
{
    int t = threadIdx.x;
    int x = blockIdx.x * 64 + (t & 63);
    int y = blockIdx.y * 4 + (t >> 6);
    int b = blockIdx.z;
    int idx = (b * HH + y) * WW + x;
    o[(size_t)b * HWP + (y + PAD_T) * WP + (x + PAD_L)] = a[idx] * c[idx];
}

extern "C" void kernel_launch(void* const* d_in, const int* in_sizes, int n_in,
                              void* d_out, int out_size, void* d_ws, size_t ws_size,
                              hipStream_t stream)
{
    const float* feat_init  = (const float*)d_in[0];
    const float* guidance   = (const float*)d_in[1];
    const float* confidence = (const float*)d_in[2];
    const float* w_oa       = (const float*)d_in[3];
    const float* b_oa       = (const float*)d_in[4];
    const float* aff_scale  = (const float*)d_in[5];
    float* out = (float*)d_out;

    // Workspace: tab u32[12N] (82.2 MB) | fc0p f32[BB*HWP] | fc1p  (96.5 MB)
    const size_t N = (size_t)NPIX;
    unsigned* tab = (unsigned*)d_ws;
    float* fc0 = (float*)(tab + 12 * N);
    float* fc1 = fc0 + (size_t)BB * HWP;

    const dim3 mgrid(WW / 64, HH / 4, BB);
    const int n4 = 2 * BB * HWP / 4;
    zero_kernel<<<(n4 + 255) / 256, 256, 0, stream>>>((float4*)fc0, n4);
    mulpad_kernel<<<mgrid, 256, 0, stream>>>(feat_init, confidence, fc0);
    conv_fused_kernel<<<2 * BB * HH, 320, 0, stream>>>(
        guidance, w_oa, b_oa, aff_scale, tab);

    const int pblocks = (WW / 64) * (HH / 4) * BB;   // 6688
    float* bufs[2] = {fc0, fc1};
    const int T = 18;
    for (int i = 0; i < T; ++i) {
        const float* src = bufs[i & 1];
        if (i < T - 1) {
            float* dst = bufs[(i + 1) & 1];
            prop_step_kernel<true><<<pblocks, 256, 0, stream>>>(
                src, tab, confidence, dst);
        } else {
            prop_step_kernel<false><<<pblocks, 256, 0, stream>>>(
                src, tab, confidence, out);
        }
    }
}

// Round 7
// 533.736 us; speedup vs baseline: 1.1727x; 1.0461x over previous
//
#include <hip/hip_runtime.h>

#define BB 4
#define HH 352
#define WW 1216
#define HW (HH * WW)
#define NPIX (BB * HW)   // 1,712,128
#define TX 4             // pixels per thread in conv kernels

// Padded propagation buffer: apron of zeros so bilinear gathers need no
// bounds checks. |rel| <= 4 (encode clamp) => corners in [y-4,y+5]x[x-4,x+5].
#define PAD_T 5
#define PAD_L 8
#define HP (HH + 2 * PAD_T)      // 362
#define WP (WW + 2 * PAD_L)      // 1232
#define HWP (HP * WP)            // 445,984

// Prop LDS tile (R15): block covers 64x8 px; samples live in rows [0,15],
// cols [0,71]; stage 17 x 76 (stride 76: banks shift 12/row, ~2 lanes/bank).
#define TROWS 17
#define TCOLS 76
#define TSIZE (TROWS * TCOLS)    // 1292

// AoS tap table (R14): one 48B record per px, 16B-aligned:
//   u32 slot 0..7 : packed coords, q=round((rel+4)*8192), y lo16, x hi16,
//                   neighbor order n=0..7 (tap k = n<4 ? n : n+1).
//   u32 slot 8..11: 8 affinities u16 (taps 0,1,2,3,5,6,7,8), q=(a+1)*20000.
// Center-tap affinity reconstructed: ak4 = 1 - sum(others) (TGASS identity).
//
// NOTES carried forward:
//  R3: every loop indexing a register array MUST be fully unrolled (runtime
//      index -> scratch demotion, 5.4 GB spill, 8x regression).
//  R5: WRITE_SIZE includes ~160 MB of harness 0xAA-poison writeback.
//  R7: prop is NOT HBM-bound at 27 us/step (-26% bytes -> 0 time change).
//  R8: LDS tile staging, gathers via ds_read2_b32.
//  R9/R10/R13: merged 24-out conv DEAD END: allocator caps conv blocks at
//      52-100 arch VGPR regardless of launch_bounds; acc > ~32 floats ->
//      AGPR demotion -> 3-5 VALU ops per FMA.
//  R11: 2-role fused conv = 147.6 us; roles interleaved per XCD. KEEP.
//  R12: 3x8-out roles = 165 us (splitting multiplies the fixed load cost).
//  R14: 48B AoS tap records: 17 plane loads -> 3 dwordx4. 579.6 -> 558.3.
//       Prop now ~22.6 us/step, VALU-issue-bound (floor ~15 us/step).
//  R15 (this round): conv flattened to 256-thr blocks (zero idle lanes,
//       4-wave packing, per-thread rv); prop 64x8 tiles (staging 3.86 ->
//       2.52 floats/px, half the block fixed costs). Numerics unchanged.

// ---------------------------------------------------------------------------
// Kernel A (role-fused, flattened): grid 3344 = 8 XCDs x 209 blk-pairs.
//   xcd = bid&7, u = bid>>3, role = u&1, blk = xcd*209 + (u>>1).
// Each block: 256 threads x one 4-px group; group gg = blk*256+tid;
// row = gg/304, x0 = (gg%304)*4.  428,032 groups = 1672 blocks exactly.
// role 0: ch 0..15 -> coord slots 0..7. role 1: ch 16..23 + TGASS -> 8..11.
// Channel mapping (verified R2): neighbor n: dy = ch[2n], dx = ch[2n+1].
// ---------------------------------------------------------------------------
__global__ __launch_bounds__(256) void conv_fused_kernel(
    const float* __restrict__ guid, const float* __restrict__ w,
    const float* __restrict__ bias, const float* __restrict__ scale_p,
    unsigned* __restrict__ tab)
{
    int tid = threadIdx.x;
    int bid = blockIdx.x;                  // 0..3343
    int xcd = bid & 7;
    int u = bid >> 3;                      // 0..417
    int role = u & 1;                      // block-uniform
    int blk = xcd * 209 + (u >> 1);        // 0..1671
    int gg = blk * 256 + tid;              // 4-px group id, 0..428031
    int row = gg / 304;                    // 0..1407
    int x0 = (gg % 304) * TX;
    int y = row % HH;
    int b = row / HH;
    const float* gb = guid + (size_t)b * 8 * HW;

    if (role == 0) {
        // ---------------- offsets body (R3 verbatim, rv per-thread) -------
        float acc[16][TX];
#pragma unroll
        for (int o = 0; o < 16; ++o) {
            float bv = bias[o];
#pragma unroll
            for (int tx = 0; tx < TX; ++tx) acc[o][tx] = bv;
        }

#pragma unroll 1
        for (int c = 0; c < 8; ++c) {
            float g[3][6];
#pragma unroll
            for (int r = 0; r < 3; ++r) {
                int yy = y + r - 1;
                bool rv = (yy >= 0) && (yy < HH);
                const float* gr = gb + (size_t)c * HW + (size_t)yy * WW;
                if (rv) {
                    const float4 m = *(const float4*)(gr + x0);
                    g[r][1] = m.x; g[r][2] = m.y; g[r][3] = m.z; g[r][4] = m.w;
                    g[r][0] = (x0 > 0) ? gr[x0 - 1] : 0.f;
                    g[r][5] = (x0 + TX < WW) ? gr[x0 + TX] : 0.f;
                } else {
#pragma unroll
                    for (int i = 0; i < 6; ++i) g[r][i] = 0.f;
                }
            }
#pragma unroll
            for (int r = 0; r < 3; ++r) {
#pragma unroll
                for (int i = 0; i < 3; ++i) {
                    int tap = r * 3 + i;
#pragma unroll
                    for (int o = 0; o < 16; ++o) {
                        float wv = w[o * 72 + c * 9 + tap];  // uniform -> s_load
#pragma unroll
                        for (int tx = 0; tx < TX; ++tx)
                            acc[o][tx] = fmaf(wv, g[r][i + tx], acc[o][tx]);
                    }
                }
            }
        }

        int idx0 = row * WW + x0;
#pragma unroll
        for (int tx = 0; tx < TX; ++tx) {
            unsigned cw8[8];
#pragma unroll
            for (int n = 0; n < 8; ++n) {
                int k = (n < 4) ? n : n + 1;
                float ky = (float)(k / 3 - 1), kx = (float)(k % 3 - 1);
                float yr = ky + acc[2 * n][tx];
                float xr = kx + acc[2 * n + 1][tx];
                int yq = (int)lrintf((yr + 4.f) * 8192.f);
                int xq = (int)lrintf((xr + 4.f) * 8192.f);
                yq = min(max(yq, 0), 65535);
                xq = min(max(xq, 0), 65535);
                cw8[n] = (unsigned)yq | ((unsigned)xq << 16);
            }
            unsigned* tp = tab + (size_t)(idx0 + tx) * 12;
            *(uint4*)(tp)     = make_uint4(cw8[0], cw8[1], cw8[2], cw8[3]);
            *(uint4*)(tp + 4) = make_uint4(cw8[4], cw8[5], cw8[6], cw8[7]);
        }
    } else {
        // ---------------- affinity body (R3 verbatim, rv per-thread) ------
        float acc[8][TX];
#pragma unroll
        for (int o = 0; o < 8; ++o) {
            float bv = bias[16 + o];
#pragma unroll
            for (int tx = 0; tx < TX; ++tx) acc[o][tx] = bv;
        }

#pragma unroll 1
        for (int c = 0; c < 8; ++c) {
            float g[3][6];
#pragma unroll
            for (int r = 0; r < 3; ++r) {
                int yy = y + r - 1;
                bool rv = (yy >= 0) && (yy < HH);
                const float* gr = gb + (size_t)c * HW + (size_t)yy * WW;
                if (rv) {
                    const float4 m = *(const float4*)(gr + x0);
                    g[r][1] = m.x; g[r][2] = m.y; g[r][3] = m.z; g[r][4] = m.w;
                    g[r][0] = (x0 > 0) ? gr[x0 - 1] : 0.f;
                    g[r][5] = (x0 + TX < WW) ? gr[x0 + TX] : 0.f;
                } else {
#pragma unroll
                    for (int i = 0; i < 6; ++i) g[r][i] = 0.f;
                }
            }
#pragma unroll
            for (int r = 0; r < 3; ++r) {
#pragma unroll
                for (int i = 0; i < 3; ++i) {
                    int tap = r * 3 + i;
#pragma unroll
                    for (int o = 0; o < 8; ++o) {
                        float wv = w[(16 + o) * 72 + c * 9 + tap];
#pragma unroll
                        for (int tx = 0; tx < TX; ++tx)
                            acc[o][tx] = fmaf(wv, g[r][i + tx], acc[o][tx]);
                    }
                }
            }
        }

        float sc = scale_p[0] + 1e-8f;
        int idx0 = row * WW + x0;
#pragma unroll
        for (int tx = 0; tx < TX; ++tx) {
            float a[8];
            float asum = 1e-4f;
#pragma unroll
            for (int n = 0; n < 8; ++n) {
                a[n] = tanhf(acc[n][tx]) / sc;
                asum += fabsf(a[n]);
            }
            asum = fmaxf(asum, 1.0f);
            unsigned q8[8];
#pragma unroll
            for (int n = 0; n < 8; ++n) {
                a[n] = a[n] / asum;
                int q = (int)lrintf((a[n] + 1.f) * 20000.f);
                q = min(max(q, 0), 65535);
                q8[n] = (unsigned)q;
            }
            unsigned* tp = tab + (size_t)(idx0 + tx) * 12 + 8;
            *(uint4*)(tp) = make_uint4(q8[0] | (q8[1] << 16), q8[2] | (q8[3] << 16),
                                       q8[4] | (q8[5] << 16), q8[6] | (q8[7] << 16));
        }
    }
}

// ---------------------------------------------------------------------------
// Kernel B: one propagation step. Block = 64x8 px (512 thr, R15); feat tile
// (17x76) staged in LDS, bilinear corners via ds_read2_b32 pairs (R8).
// Tables: one 48B AoS record per px -> 3 dwordx4 loads (R14).
// Grid 3344 = 8 XCDs x 418; per XCD 22 contiguous ybands (176 rows) matching
// conv's per-XCD slab, so tab stays XCD-L2-local across all 18 steps.
// Tile coords: sample row = ly + qy/8192, rows [0,15] of 17; cols [0,71] of 76.
// ---------------------------------------------------------------------------
template <bool MULCONF>
__global__ __launch_bounds__(512) void prop_step_kernel(
    const float* __restrict__ fsrc, const unsigned* __restrict__ tab,
    const float* __restrict__ conf, float* __restrict__ dst)
{
    __shared__ float tile[TSIZE];

    int bid = blockIdx.x;                 // 0..3343
    int xcd = bid & 7;
    int s = bid >> 3;                     // 0..417
    int gid = xcd * 418 + s;              // 0..3343, XCD-contiguous
    int b = gid / 836;                    // 836 = 19 * 44 blocks per image
    int r2 = gid % 836;
    int yband = r2 / 19;                  // 0..43
    int xb = r2 % 19;                     // 0..18
    int t = threadIdx.x;
    int lx = t & 63, ly = t >> 6;         // ly 0..7
    int x = xb * 64 + lx;
    int y = yband * 8 + ly;
    int idx = (b * HH + y) * WW + x;

    // Whole tap record in 3 aligned dwordx4 loads; they fly across the
    // staging barrier below.
    const unsigned* tp = tab + (size_t)idx * 12;
    uint4 t0 = *(const uint4*)(tp);       // coords n0..3
    uint4 t1 = *(const uint4*)(tp + 4);   // coords n4..7
    uint4 t2 = *(const uint4*)(tp + 8);   // affs u16 x8 (taps 0..3,5..8)
    float cv = MULCONF ? conf[idx] : 0.f;

    // Stage tile: unpadded rows [y0-4, y0+12], cols [x0-4, x0+71]; all inside
    // the padded buffer (row y0-4 -> padded y0+1 >= 1; last band row 356 ->
    // padded 361 = HP-1).
    {
        const float* gsrc = fsrc + (size_t)b * HWP
                          + (size_t)(yband * 8 + 1) * WP + (xb * 64 + 4);
        for (int i = t; i < TSIZE; i += 512)
            tile[i] = gsrc[(i / TCOLS) * WP + (i % TCOLS)];
    }

    unsigned cw[8] = {t0.x, t0.y, t0.z, t0.w, t1.x, t1.y, t1.z, t1.w};
    float ak[9];
    ak[0] = fmaf((float)(t2.x & 0xffffu), 5e-5f, -1.f);
    ak[1] = fmaf((float)(t2.x >> 16),     5e-5f, -1.f);
    ak[2] = fmaf((float)(t2.y & 0xffffu), 5e-5f, -1.f);
    ak[3] = fmaf((float)(t2.y >> 16),     5e-5f, -1.f);
    ak[5] = fmaf((float)(t2.z & 0xffffu), 5e-5f, -1.f);
    ak[6] = fmaf((float)(t2.z >> 16),     5e-5f, -1.f);
    ak[7] = fmaf((float)(t2.w & 0xffffu), 5e-5f, -1.f);
    ak[8] = fmaf((float)(t2.w >> 16),     5e-5f, -1.f);
    ak[4] = 1.f - (((ak[0] + ak[1]) + (ak[2] + ak[3]))
                 + ((ak[5] + ak[6]) + (ak[7] + ak[8])));

    __syncthreads();

    float fy = (float)ly;
    float fx = (float)lx;
    float res = ak[4] * tile[(ly + 4) * TCOLS + (lx + 4)];  // exact center tap
#pragma unroll
    for (int n = 0; n < 8; ++n) {
        float ys = fmaf((float)(cw[n] & 0xffffu), 1.f / 8192.f, fy);
        float xs = fmaf((float)(cw[n] >> 16),     1.f / 8192.f, fx);
        float y0f = floorf(ys), x0f = floorf(xs);
        float wy1 = ys - y0f, wx1 = xs - x0f;
        float wy0 = 1.f - wy1, wx0 = 1.f - wx1;
        int o = (int)y0f * TCOLS + (int)x0f;
        float v00 = tile[o],         v01 = tile[o + 1];          // ds_read2
        float v10 = tile[o + TCOLS], v11 = tile[o + TCOLS + 1];  // ds_read2
        float sv = wy0 * (wx0 * v00 + wx1 * v01) + wy1 * (wx0 * v10 + wx1 * v11);
        int k = (n < 4) ? n : n + 1;
        res = fmaf(ak[k], sv, res);
    }
    if (MULCONF) {
        res *= cv;
        dst[(size_t)b * HWP + (y + PAD_T) * WP + (x + PAD_L)] = res;
    } else {
        dst[idx] = res;
    }
}

// Zero both padded buffers (apron must be 0; ws is poisoned 0xAA each launch).
__global__ __launch_bounds__(256) void zero_kernel(float4* __restrict__ p, int n4)
{
    int i = blockIdx.x * blockDim.x + threadIdx.x;
    if (i < n4) p[i] = make_float4(0.f, 0.f, 0.f, 0.f);
}

// fc0[padded interior] = feat_init * conf
__global__ __launch_bounds__(256) void mulpad_kernel(
    const float* __restrict__ a, const float* __restrict__ c, float* __restrict__ o)
{
    int t = threadIdx.x;
    int x = blockIdx.x * 64 + (t & 63);
    int y = blockIdx.y * 4 + (t >> 6);
    int b = blockIdx.z;
    int idx = (b * HH + y) * WW + x;
    o[(size_t)b * HWP + (y + PAD_T) * WP + (x + PAD_L)] = a[idx] * c[idx];
}

extern "C" void kernel_launch(void* const* d_in, const int* in_sizes, int n_in,
                              void* d_out, int out_size, void* d_ws, size_t ws_size,
                              hipStream_t stream)
{
    const float* feat_init  = (const float*)d_in[0];
    const float* guidance   = (const float*)d_in[1];
    const float* confidence = (const float*)d_in[2];
    const float* w_oa       = (const float*)d_in[3];
    const float* b_oa       = (const float*)d_in[4];
    const float* aff_scale  = (const float*)d_in[5];
    float* out = (float*)d_out;

    // Workspace: tab u32[12N] (82.2 MB) | fc0p f32[BB*HWP] | fc1p  (96.5 MB)
    const size_t N = (size_t)NPIX;
    unsigned* tab = (unsigned*)d_ws;
    float* fc0 = (float*)(tab + 12 * N);
    float* fc1 = fc0 + (size_t)BB * HWP;

    const dim3 mgrid(WW / 64, HH / 4, BB);
    const int n4 = 2 * BB * HWP / 4;
    zero_kernel<<<(n4 + 255) / 256, 256, 0, stream>>>((float4*)fc0, n4);
    mulpad_kernel<<<mgrid, 256, 0, stream>>>(feat_init, confidence, fc0);
    conv_fused_kernel<<<2 * 1672, 256, 0, stream>>>(
        guidance, w_oa, b_oa, aff_scale, tab);

    const int pblocks = (WW / 64) * (HH / 8) * BB;   // 3344
    float* bufs[2] = {fc0, fc1};
    const int T = 18;
    for (int i = 0; i < T; ++i) {
        const float* src = bufs[i & 1];
        if (i < T - 1) {
            float* dst = bufs[(i + 1) & 1];
            prop_step_kernel<true><<<pblocks, 512, 0, stream>>>(
                src, tab, confidence, dst);
        } else {
            prop_step_kernel<false><<<pblocks, 512, 0, stream>>>(
                src, tab, confidence, out);
        }
    }
}